// Round 2
// baseline (671.190 us; speedup 1.0000x reference)
//
#include <hip/hip_runtime.h>
#include <math.h>

#define BN 1024      // batch
#define DIN 3072
#define DE 256
#define NK 6

constexpr double EPS = 0.1;
constexpr double LOG2E = 1.4426950408889634073599246810019;
constexpr double K2 = 10.0 * LOG2E;                    // (1/eps) * log2(e)
constexpr double EPS_LOGA = -0.69314718055994530942;   // eps * (-log(1024)) == -ln2

#if __has_builtin(__builtin_amdgcn_exp2f)
#define EXP2F __builtin_amdgcn_exp2f
#else
#define EXP2F exp2f
#endif

// ---------------- critic GEMM + row-normalize ----------------
// block = 256 threads, computes 16 rows x 256 cols of F = normalize(X @ Wc + bc)
__global__ __launch_bounds__(256) void critic_kernel(
    const float* __restrict__ x, const float* __restrict__ xp,
    const float* __restrict__ y, const float* __restrict__ yp,
    const float* __restrict__ Wc, const float* __restrict__ bc,
    float* __restrict__ F) {
  __shared__ float xs[16][DE + 1];
  __shared__ double red[4];
  const int t = threadIdx.x;
  const int R0 = blockIdx.x * 16;          // global row among 4096
  const int m = R0 >> 10;                  // which input matrix
  const int r0 = R0 & 1023;                // row within matrix
  const float* src = (m == 0) ? x : (m == 1) ? xp : (m == 2) ? y : yp;

  float acc[16];
#pragma unroll
  for (int u = 0; u < 16; ++u) acc[u] = 0.f;

  for (int kc = 0; kc < DIN; kc += DE) {
    __syncthreads();
#pragma unroll
    for (int u = 0; u < 16; ++u)
      xs[u][t] = src[(size_t)(r0 + u) * DIN + kc + t];
    __syncthreads();
#pragma unroll 4
    for (int k = 0; k < DE; ++k) {
      float w = Wc[(size_t)(kc + k) * DE + t];
#pragma unroll
      for (int u = 0; u < 16; ++u) acc[u] += xs[u][k] * w;
    }
  }
#pragma unroll
  for (int u = 0; u < 16; ++u) acc[u] += bc[t];

  const int lane = t & 63, w = t >> 6;
  for (int u = 0; u < 16; ++u) {
    __syncthreads();   // protect red[] from previous iteration's readers
    double ss = (double)acc[u] * (double)acc[u];
#pragma unroll
    for (int off = 32; off; off >>= 1) ss += __shfl_down(ss, off);
    if (lane == 0) red[w] = ss;
    __syncthreads();
    double nrm2 = red[0] + red[1] + red[2] + red[3];
    double rn = 1.0 / sqrt(nrm2);
    F[((size_t)m * BN + (r0 + u)) * DE + t] = (float)((double)acc[u] * rn);
  }
}

// ---------------- 6 pairwise cosine-distance matrices (+ transposed copy) ----
// grid (16,16,6); block 256; 64x64 tile per block; K=256 in chunks of 64
__global__ __launch_bounds__(256) void cosine_kernel(
    const float* __restrict__ F, float* __restrict__ C, float* __restrict__ CT) {
  __shared__ float As[64][65];
  __shared__ float Bs[64][65];
  const int pa[NK] = {0, 0, 1, 1, 0, 2};
  const int pb[NK] = {2, 3, 2, 3, 1, 3};
  const int p = blockIdx.z;
  const int ti = blockIdx.y, tj = blockIdx.x;
  const int t = threadIdx.x;
  const int ty = t >> 4, tx = t & 15;
  const float* FA = F + (size_t)pa[p] * BN * DE + (size_t)ti * 64 * DE;
  const float* FB = F + (size_t)pb[p] * BN * DE + (size_t)tj * 64 * DE;

  float acc[4][4] = {};
  for (int kc = 0; kc < DE; kc += 64) {
    __syncthreads();
    for (int idx = t; idx < 64 * 64; idx += 256) {
      int r = idx >> 6, c = idx & 63;
      As[r][c] = FA[(size_t)r * DE + kc + c];
      Bs[r][c] = FB[(size_t)r * DE + kc + c];
    }
    __syncthreads();
#pragma unroll 8
    for (int kk = 0; kk < 64; ++kk) {
      float a[4], b[4];
#pragma unroll
      for (int u = 0; u < 4; ++u) a[u] = As[ty * 4 + u][kk];
#pragma unroll
      for (int v = 0; v < 4; ++v) b[v] = Bs[tx * 4 + v][kk];
#pragma unroll
      for (int u = 0; u < 4; ++u)
#pragma unroll
        for (int v = 0; v < 4; ++v) acc[u][v] += a[u] * b[v];
    }
  }
#pragma unroll
  for (int u = 0; u < 4; ++u)
#pragma unroll
    for (int v = 0; v < 4; ++v) {
      int gi = ti * 64 + ty * 4 + u;
      int gj = tj * 64 + tx * 4 + v;
      float val = 1.f - acc[u][v];
      C[((size_t)p * BN + gi) * BN + gj] = val;
      CT[((size_t)p * BN + gj) * BN + gi] = val;
    }
}

// ---------------- one Sinkhorn half-step (row direction) --------------------
// out[k,i] = -ln2 - eps * ln( sum_j exp2( (dual[k,j] - M[k,i,j]) * K2 ) )
// Used for both halves: f-update with (C, g) and g-update with (CT, f).
__global__ __launch_bounds__(256) void sink_half_kernel(
    const float* __restrict__ M, const double* __restrict__ dual,
    double* __restrict__ out, int it, const int* __restrict__ nit) {
  if (it >= *nit) return;
  __shared__ double red[4];
  const int k = blockIdx.x >> 10, i = blockIdx.x & 1023;
  const float4* row4 = (const float4*)(M + ((size_t)k << 20) + ((size_t)i << 10));
  const double* dk = dual + ((size_t)k << 10);
  const int t = threadIdx.x;

  float4 cv = row4[t];
  int j = t * 4;
  double s = 0.0;
  s += (double)EXP2F((float)((dk[j + 0] - (double)cv.x) * K2));
  s += (double)EXP2F((float)((dk[j + 1] - (double)cv.y) * K2));
  s += (double)EXP2F((float)((dk[j + 2] - (double)cv.z) * K2));
  s += (double)EXP2F((float)((dk[j + 3] - (double)cv.w) * K2));

#pragma unroll
  for (int off = 32; off; off >>= 1) s += __shfl_down(s, off);
  if ((t & 63) == 0) red[t >> 6] = s;
  __syncthreads();
  if (t == 0) {
    double tot = red[0] + red[1] + red[2] + red[3];
    out[blockIdx.x] = EPS_LOGA - EPS * log(tot);
  }
}

// ---------------- W_k row partials: sum_j P_ij * C_ij -----------------------
__global__ __launch_bounds__(256) void wsum_kernel(
    const float* __restrict__ C, const double* __restrict__ f,
    const double* __restrict__ g, double* __restrict__ Wp) {
  __shared__ double red[4];
  const int k = blockIdx.x >> 10, i = blockIdx.x & 1023;
  const float4* row4 = (const float4*)(C + ((size_t)k << 20) + ((size_t)i << 10));
  const double* gk = g + ((size_t)k << 10);
  const double fi = f[blockIdx.x];
  const int t = threadIdx.x;

  float4 cv = row4[t];
  int j = t * 4;
  double s = 0.0;
  {
    double c0 = (double)cv.x, c1 = (double)cv.y, c2 = (double)cv.z, c3 = (double)cv.w;
    s += (double)EXP2F((float)((fi + gk[j + 0] - c0) * K2)) * c0;
    s += (double)EXP2F((float)((fi + gk[j + 1] - c1) * K2)) * c1;
    s += (double)EXP2F((float)((fi + gk[j + 2] - c2) * K2)) * c2;
    s += (double)EXP2F((float)((fi + gk[j + 3] - c3) * K2)) * c3;
  }
#pragma unroll
  for (int off = 32; off; off >>= 1) s += __shfl_down(s, off);
  if ((t & 63) == 0) red[t >> 6] = s;
  __syncthreads();
  if (t == 0) Wp[blockIdx.x] = red[0] + red[1] + red[2] + red[3];
}

// ---------------- final signed scalar ---------------------------------------
__global__ __launch_bounds__(256) void final_kernel(
    const double* __restrict__ Wp, float* __restrict__ out) {
  __shared__ double red[4];
  const int t = threadIdx.x;
  double s = 0.0;
  for (int idx = t; idx < NK * BN; idx += 256) {
    double sign = (idx < 4 * BN) ? 1.0 : -2.0;
    s += sign * Wp[idx];
  }
#pragma unroll
  for (int off = 32; off; off >>= 1) s += __shfl_down(s, off);
  if ((t & 63) == 0) red[t >> 6] = s;
  __syncthreads();
  if (t == 0) out[0] = (float)(red[0] + red[1] + red[2] + red[3]);
}

extern "C" void kernel_launch(void* const* d_in, const int* in_sizes, int n_in,
                              void* d_out, int out_size, void* d_ws, size_t ws_size,
                              hipStream_t stream) {
  (void)in_sizes; (void)n_in; (void)out_size; (void)ws_size;
  const float* x  = (const float*)d_in[0];
  const float* xp = (const float*)d_in[1];
  const float* y  = (const float*)d_in[2];
  const float* yp = (const float*)d_in[3];
  const float* Wc = (const float*)d_in[4];
  const float* bc = (const float*)d_in[5];
  const int*  nit = (const int*)d_in[6];

  char* ws = (char*)d_ws;
  size_t offC  = 0;
  size_t offCT = offC  + (size_t)NK * BN * BN * 4;   // 25.2 MB
  size_t offF  = offCT + (size_t)NK * BN * BN * 4;   // 25.2 MB
  size_t offf  = offF  + (size_t)4 * BN * DE * 4;    // 4 MB
  size_t offg  = offf  + (size_t)NK * BN * 8;
  size_t offW  = offg  + (size_t)NK * BN * 8;
  float*  C  = (float*)(ws + offC);
  float*  CT = (float*)(ws + offCT);
  float*  F  = (float*)(ws + offF);
  double* f  = (double*)(ws + offf);
  double* g  = (double*)(ws + offg);
  double* Wp = (double*)(ws + offW);

  // f = g = 0 (must re-init every call; ws is not re-poisoned between replays)
  hipMemsetAsync(f, 0, (size_t)NK * BN * 8 * 2, stream);

  critic_kernel<<<256, 256, 0, stream>>>(x, xp, y, yp, Wc, bc, F);
  cosine_kernel<<<dim3(16, 16, NK), 256, 0, stream>>>(F, C, CT);

  const int MAXIT = 20;  // actual count guarded device-side via *nit
  for (int it = 0; it < MAXIT; ++it) {
    sink_half_kernel<<<NK * BN, 256, 0, stream>>>(C,  g, f, it, nit);  // f-update
    sink_half_kernel<<<NK * BN, 256, 0, stream>>>(CT, f, g, it, nit);  // g-update
  }
  wsum_kernel<<<NK * BN, 256, 0, stream>>>(C, f, g, Wp);
  final_kernel<<<1, 256, 0, stream>>>(Wp, (float*)d_out);
}

// Round 3
// 492.967 us; speedup vs baseline: 1.3615x; 1.3615x over previous
//
#include <hip/hip_runtime.h>
#include <math.h>

#define BN 1024      // batch
#define DIN 3072
#define DE 256
#define NK 6
#define KS 4         // critic split-K factor
#define KC (DIN / KS)

constexpr double EPS = 0.1;
constexpr double LOG2E = 1.4426950408889634073599246810019;
constexpr double K2 = 10.0 * LOG2E;   // (1/eps)*log2(e)

// ---------------- critic GEMM (split-K partials) ----------------------------
// grid (64 rowtiles, 4 coltiles, KS); block 256; 64x64 tile, 4x4 micro-tile.
// LDS layout transposed: As[k][row], Bs[k][col] -> ds_read_b128 fragments.
__global__ __launch_bounds__(256) void critic_gemm(
    const float* __restrict__ x, const float* __restrict__ xp,
    const float* __restrict__ y, const float* __restrict__ yp,
    const float* __restrict__ Wc, float* __restrict__ Pp) {
  __shared__ float As[64][68];
  __shared__ float Bs[64][68];
  const int t = threadIdx.x;
  const int rt = blockIdx.x, ct = blockIdx.y, ks = blockIdx.z;
  const int R0 = rt * 64;
  const int m = R0 >> 10;
  const int r0 = R0 & 1023;
  const float* src = (m == 0) ? x : (m == 1) ? xp : (m == 2) ? y : yp;
  const int ty = t >> 4, tx = t & 15;

  float acc[4][4] = {};
  for (int kc0 = 0; kc0 < KC; kc0 += 64) {
    const int kc = ks * KC + kc0;
    __syncthreads();
    // stage A transposed (row-major source -> As[k][row])
#pragma unroll
    for (int i = 0; i < 4; ++i) {
      int r = (t >> 4) + 16 * i, q = t & 15;
      float4 av = *(const float4*)&src[(size_t)(r0 + r) * DIN + kc + 4 * q];
      As[4 * q + 0][r] = av.x; As[4 * q + 1][r] = av.y;
      As[4 * q + 2][r] = av.z; As[4 * q + 3][r] = av.w;
    }
    // stage B (Wc already [k][col]) -> Bs[k][col]
#pragma unroll
    for (int i = 0; i < 4; ++i) {
      int k = t >> 2, cq = (t & 3) + 4 * i;
      float4 bv = *(const float4*)&Wc[(size_t)(kc + k) * DE + ct * 64 + 4 * cq];
      *(float4*)&Bs[k][4 * cq] = bv;
    }
    __syncthreads();
#pragma unroll 8
    for (int kk = 0; kk < 64; ++kk) {
      float4 a = *(const float4*)&As[kk][4 * ty];
      float4 b = *(const float4*)&Bs[kk][4 * tx];
      float av[4] = {a.x, a.y, a.z, a.w};
      float bv[4] = {b.x, b.y, b.z, b.w};
#pragma unroll
      for (int u = 0; u < 4; ++u)
#pragma unroll
        for (int v = 0; v < 4; ++v) acc[u][v] += av[u] * bv[v];
    }
  }
#pragma unroll
  for (int u = 0; u < 4; ++u) {
    int gi = R0 + ty * 4 + u;
    float4 o = {acc[u][0], acc[u][1], acc[u][2], acc[u][3]};
    *(float4*)&Pp[((size_t)ks * 4096 + gi) * DE + ct * 64 + 4 * tx] = o;
  }
}

// ---------------- combine split-K partials + bias + row-normalize -----------
__global__ __launch_bounds__(256) void critic_norm(
    const float* __restrict__ Pp, const float* __restrict__ bc,
    float* __restrict__ F) {
  __shared__ double red[4];
  __shared__ double nrm2s;
  const int row = blockIdx.x, t = threadIdx.x;
  double val = (double)bc[t];
#pragma unroll
  for (int ks = 0; ks < KS; ++ks)
    val += (double)Pp[((size_t)ks * 4096 + row) * DE + t];
  double ss = val * val;
#pragma unroll
  for (int off = 32; off; off >>= 1) ss += __shfl_down(ss, off);
  if ((t & 63) == 0) red[t >> 6] = ss;
  __syncthreads();
  if (t == 0) nrm2s = red[0] + red[1] + red[2] + red[3];
  __syncthreads();
  double rn = 1.0 / sqrt(nrm2s);
  F[(size_t)row * DE + t] = (float)(val * rn);
}

// ---------------- 6 cosine matrices -> E = exp(-C/eps) and E^T --------------
// grid (16,16,6); 64x64 tile per block.
__global__ __launch_bounds__(256) void cosine_e(
    const float* __restrict__ F, float* __restrict__ E, float* __restrict__ ET) {
  __shared__ float As[64][68];
  __shared__ float Bs[64][68];
  const int pa[NK] = {0, 0, 1, 1, 0, 2};
  const int pb[NK] = {2, 3, 2, 3, 1, 3};
  const int p = blockIdx.z;
  const int ti = blockIdx.y, tj = blockIdx.x;
  const int t = threadIdx.x;
  const int ty = t >> 4, tx = t & 15;
  const float* FA = F + ((size_t)pa[p] * BN + ti * 64) * DE;
  const float* FB = F + ((size_t)pb[p] * BN + tj * 64) * DE;

  float acc[4][4] = {};
  for (int kc = 0; kc < DE; kc += 64) {
    __syncthreads();
#pragma unroll
    for (int i = 0; i < 4; ++i) {
      int r = (t >> 4) + 16 * i, q = t & 15;
      float4 av = *(const float4*)&FA[(size_t)r * DE + kc + 4 * q];
      As[4 * q + 0][r] = av.x; As[4 * q + 1][r] = av.y;
      As[4 * q + 2][r] = av.z; As[4 * q + 3][r] = av.w;
      float4 bv = *(const float4*)&FB[(size_t)r * DE + kc + 4 * q];
      Bs[4 * q + 0][r] = bv.x; Bs[4 * q + 1][r] = bv.y;
      Bs[4 * q + 2][r] = bv.z; Bs[4 * q + 3][r] = bv.w;
    }
    __syncthreads();
#pragma unroll 8
    for (int kk = 0; kk < 64; ++kk) {
      float4 a = *(const float4*)&As[kk][4 * ty];
      float4 b = *(const float4*)&Bs[kk][4 * tx];
      float av[4] = {a.x, a.y, a.z, a.w};
      float bv[4] = {b.x, b.y, b.z, b.w};
#pragma unroll
      for (int u = 0; u < 4; ++u)
#pragma unroll
        for (int v = 0; v < 4; ++v) acc[u][v] += av[u] * bv[v];
    }
  }
  float e[4][4];
#pragma unroll
  for (int u = 0; u < 4; ++u) {
#pragma unroll
    for (int v = 0; v < 4; ++v) {
      double c = 1.0 - (double)acc[u][v];
      e[u][v] = (float)exp2(-c * K2);
    }
    int gi = ti * 64 + ty * 4 + u;
    float4 o = {e[u][0], e[u][1], e[u][2], e[u][3]};
    *(float4*)&E[(((size_t)p << 10) + gi) * BN + tj * 64 + 4 * tx] = o;
  }
#pragma unroll
  for (int v = 0; v < 4; ++v) {
    int gj = tj * 64 + tx * 4 + v;
    float4 o = {e[0][v], e[1][v], e[2][v], e[3][v]};
    *(float4*)&ET[(((size_t)p << 10) + gj) * BN + ti * 64 + 4 * ty] = o;
  }
}

// ---------------- u init ----------------------------------------------------
__global__ void init_u(double* __restrict__ u) {
  int i = blockIdx.x * 256 + threadIdx.x;
  if (i < 2 * NK * BN) u[i] = 1.0;
}

// ---------------- one Sinkhorn half-step as f64 matvec ----------------------
// S_i = sum_j M[k,i,j] * uin[k,j];  uout[k,i] = 1/(1024*S_i).  8 rows/block.
__global__ __launch_bounds__(256) void sink_half(
    const float* __restrict__ M, const double* __restrict__ uin,
    double* __restrict__ uout, int it, const int* __restrict__ nit) {
  if (it >= *nit) return;
  __shared__ double red[4][8];
  const int t = threadIdx.x;
  const int R0 = blockIdx.x * 8;
  const int k = R0 >> 10;
  const double* u = uin + ((size_t)k << 10);
  double u0 = u[4 * t], u1 = u[4 * t + 1], u2 = u[4 * t + 2], u3 = u[4 * t + 3];
  const float4* Mp = (const float4*)(M + ((size_t)R0 << 10));
  double s[8];
#pragma unroll
  for (int r = 0; r < 8; ++r) {
    float4 ev = Mp[(r << 8) + t];
    s[r] = (double)ev.x * u0 + (double)ev.y * u1 +
           (double)ev.z * u2 + (double)ev.w * u3;
  }
  const int lane = t & 63, w = t >> 6;
#pragma unroll
  for (int r = 0; r < 8; ++r)
#pragma unroll
    for (int off = 32; off; off >>= 1) s[r] += __shfl_down(s[r], off);
  if (lane == 0)
#pragma unroll
    for (int r = 0; r < 8; ++r) red[w][r] = s[r];
  __syncthreads();
  if (t < 8) {
    double S = red[0][t] + red[1][t] + red[2][t] + red[3][t];
    uout[R0 + t] = 1.0 / (1024.0 * S);
  }
}

// ---------------- W row partials: uf_i * sum_j E*ug_j*C, C = -eps*ln(E) -----
__global__ __launch_bounds__(256) void wsum_kernel(
    const float* __restrict__ E, const double* __restrict__ uf,
    const double* __restrict__ ug, double* __restrict__ Wp) {
  __shared__ double red[4][8];
  const int t = threadIdx.x;
  const int R0 = blockIdx.x * 8;
  const int k = R0 >> 10;
  const double* u = ug + ((size_t)k << 10);
  double u0 = u[4 * t], u1 = u[4 * t + 1], u2 = u[4 * t + 2], u3 = u[4 * t + 3];
  const float4* Ep = (const float4*)(E + ((size_t)R0 << 10));
  double s[8];
#pragma unroll
  for (int r = 0; r < 8; ++r) {
    float4 ev = Ep[(r << 8) + t];
    double e0 = ev.x, e1 = ev.y, e2 = ev.z, e3 = ev.w;
    s[r] = e0 * u0 * (-EPS * log(e0)) + e1 * u1 * (-EPS * log(e1)) +
           e2 * u2 * (-EPS * log(e2)) + e3 * u3 * (-EPS * log(e3));
  }
  const int lane = t & 63, w = t >> 6;
#pragma unroll
  for (int r = 0; r < 8; ++r)
#pragma unroll
    for (int off = 32; off; off >>= 1) s[r] += __shfl_down(s[r], off);
  if (lane == 0)
#pragma unroll
    for (int r = 0; r < 8; ++r) red[w][r] = s[r];
  __syncthreads();
  if (t < 8) {
    double S = red[0][t] + red[1][t] + red[2][t] + red[3][t];
    Wp[R0 + t] = uf[R0 + t] * S;
  }
}

// ---------------- final signed scalar ---------------------------------------
__global__ __launch_bounds__(256) void final_kernel(
    const double* __restrict__ Wp, float* __restrict__ out) {
  __shared__ double red[4];
  const int t = threadIdx.x;
  double s = 0.0;
  for (int idx = t; idx < NK * BN; idx += 256) {
    double sign = ((idx >> 10) < 4) ? 1.0 : -2.0;
    s += sign * Wp[idx];
  }
#pragma unroll
  for (int off = 32; off; off >>= 1) s += __shfl_down(s, off);
  if ((t & 63) == 0) red[t >> 6] = s;
  __syncthreads();
  if (t == 0) out[0] = (float)(red[0] + red[1] + red[2] + red[3]);
}

extern "C" void kernel_launch(void* const* d_in, const int* in_sizes, int n_in,
                              void* d_out, int out_size, void* d_ws, size_t ws_size,
                              hipStream_t stream) {
  (void)in_sizes; (void)n_in; (void)out_size; (void)ws_size;
  const float* x  = (const float*)d_in[0];
  const float* xp = (const float*)d_in[1];
  const float* y  = (const float*)d_in[2];
  const float* yp = (const float*)d_in[3];
  const float* Wc = (const float*)d_in[4];
  const float* bc = (const float*)d_in[5];
  const int*  nit = (const int*)d_in[6];

  char* ws = (char*)d_ws;
  const size_t szE = (size_t)NK * BN * BN * 4;   // 25.17 MB
  size_t offE  = 0;
  size_t offET = offE + szE;
  size_t offF  = offET + szE;
  size_t offU  = offF + (size_t)4 * BN * DE * 4;
  float*  E  = (float*)(ws + offE);
  float*  ET = (float*)(ws + offET);
  float*  F  = (float*)(ws + offF);
  double* uf = (double*)(ws + offU);
  double* ug = uf + NK * BN;
  double* Wp = ug + NK * BN;
  // split-K partials alias the ET region (consumed before cosine_e writes ET)
  float* Pp = ET;

  init_u<<<(2 * NK * BN + 255) / 256, 256, 0, stream>>>(uf);
  critic_gemm<<<dim3(64, 4, KS), 256, 0, stream>>>(x, xp, y, yp, Wc, Pp);
  critic_norm<<<4096, 256, 0, stream>>>(Pp, bc, F);
  cosine_e<<<dim3(16, 16, NK), 256, 0, stream>>>(F, E, ET);

  const int MAXIT = 20;  // actual count guarded device-side via *nit
  for (int it = 0; it < MAXIT; ++it) {
    sink_half<<<NK * BN / 8, 256, 0, stream>>>(E,  ug, uf, it, nit);  // f-step
    sink_half<<<NK * BN / 8, 256, 0, stream>>>(ET, uf, ug, it, nit);  // g-step
  }
  wsum_kernel<<<NK * BN / 8, 256, 0, stream>>>(E, uf, ug, Wp);
  final_kernel<<<1, 256, 0, stream>>>(Wp, (float*)d_out);
}